// Round 9
// baseline (290.313 us; speedup 1.0000x reference)
//
#include <hip/hip_runtime.h>

typedef short bf16x8 __attribute__((ext_vector_type(8)));
typedef float f32x4 __attribute__((ext_vector_type(4)));
typedef unsigned short u16;

__device__ __forceinline__ u16 f2bf(float f) {
    unsigned u = __builtin_bit_cast(unsigned, f);
    return (u16)((u + 0x7fffu + ((u >> 16) & 1u)) >> 16);   // RNE
}

// ---------------- kernel 1 (fused pre): W-build || xpad || zero --------------
// blocks [0,512):    W-build. wb=bi: sb=wb>>4 (32 s-groups of 128), qb=wb&15.
//   thread q' = qb*256+tid, d=q'>>6, o=q'&63 -> Mp/Mm read DIRECTLY coalesced
//   (no transpose kernel needed). Both parities per block (A read once,
//   phi s_loads shared). 4-accumulator dot over k=40. Store to 16x16
//   B-fragment pidx (same layout k_spectral's LOADW expects).
// blocks [512,768):  xpad[b][r][d] bf16 (r<4096 zeros, 4096+t = x[b,t,:])
// blocks [768,896):  zero d_out (2 MiB); first zero-block zeros task counter.
__global__ __launch_bounds__(256)
void k_mid(const float* __restrict__ x, u16* __restrict__ xpad,
           const float* __restrict__ phi, const float* __restrict__ Mp,
           const float* __restrict__ Mm, const float* __restrict__ Mar,
           u16* __restrict__ wg, float* __restrict__ out,
           int* __restrict__ counter) {
    const int bi = blockIdx.x;
    if (bi < 512) {
        const int sb = bi >> 4, qb = bi & 15;
        const int q  = qb * 256 + threadIdx.x;           // q' = d*64 + o
        const int d  = q >> 6, o = q & 63;

        // 16x16 B-fragment target index for this (o,d)
        const int nt_  = o >> 4, m15_ = o & 15;
        const int ks_  = d >> 5, q4_ = (d >> 3) & 3, e_ = d & 7;
        const int pidx = ((ks_ * 4 + nt_) * 64 + (q4_ * 16 + m15_)) * 8 + e_;

        float ap[40], am[40];
        #pragma unroll
        for (int k = 0; k < 40; ++k) {                   // coalesced direct reads
            float p = Mp[k * 4096 + q], m = Mm[k * 4096 + q];
            ap[k] = p + m;
            am[k] = p - m;
        }

        #pragma unroll 2
        for (int m = 0; m < 64; ++m) {
            #pragma unroll
            for (int par = 0; par < 2; ++par) {
                const int s = sb * 128 + 2 * m + par;
                const float* ph = phi + s * 40;          // wave-uniform -> s_load
                float e0 = 0.f, e1 = 0.f, e2 = 0.f, e3 = 0.f;
                if (par == 0) {
                    #pragma unroll
                    for (int k = 0; k < 40; k += 4) {
                        e0 += ph[k] * ap[k];     e1 += ph[k + 1] * ap[k + 1];
                        e2 += ph[k + 2] * ap[k + 2]; e3 += ph[k + 3] * ap[k + 3];
                    }
                } else {
                    #pragma unroll
                    for (int k = 0; k < 40; k += 4) {
                        e0 += ph[k] * am[k];     e1 += ph[k + 1] * am[k + 1];
                        e2 += ph[k + 2] * am[k + 2]; e3 += ph[k + 3] * am[k + 3];
                    }
                }
                float ev = (e0 + e1) + (e2 + e3);
                if (s < 3) ev += Mar[o * 192 + d * 3 + s];   // fold AR term
                wg[(size_t)s * 4096 + pidx] = f2bf(ev);
            }
        }
    } else if (bi < 768) {
        const int u = bi - 512;
        #pragma unroll
        for (int i = 0; i < 4; ++i) {
            int gid = (u * 4 + i) * 256 + threadIdx.x;
            int b = gid >> 17, rem = gid & 131071;
            int r = rem >> 4, c4 = rem & 15;
            u16 o0 = 0, o1 = 0, o2 = 0, o3 = 0;
            if (r >= 4096) {
                const f32x4 v = *(const f32x4*)(x + ((b << 12) + (r - 4096)) * 64 + c4 * 4);
                o0 = f2bf(v.x); o1 = f2bf(v.y); o2 = f2bf(v.z); o3 = f2bf(v.w);
            }
            u16* p = xpad + ((b << 13) + r) * 64 + c4 * 4;
            p[0] = o0; p[1] = o1; p[2] = o2; p[3] = o3;
        }
    } else {
        const int bz = bi - 768;                         // 128 blocks x 4096 floats
        if (bz == 0 && threadIdx.x == 0) *counter = 0;
        float* po = out + bz * 4096;
        #pragma unroll
        for (int i = 0; i < 4; ++i)
            *(f32x4*)(po + (threadIdx.x + i * 256) * 4) = (f32x4){0.f, 0.f, 0.f, 0.f};
    }
}

// ---------------- kernel 2: triangular conv-GEMM (R3-exact, proven best) -----
// wave = (t-half, batch): each wave owns a 64t x 64o tile, loops over ALL s.
// B operands loaded global->reg (fragment-layout wg), FOUR buffers, prefetch
// distance 2 slice-pairs (~64 MFMAs of load cover). x window in LDS
// (XOR-swizzled, 0-conflict). setprio(1) around MFMA clusters. 2 blocks/CU.
// Measured (R3): 137-142 us, MfmaUtil 45.5%, BANK_CONFLICT 0, no spill.
__global__ __launch_bounds__(256, 2)
void k_spectral(const u16* __restrict__ xpad, const u16* __restrict__ wg,
                float* __restrict__ out, int* __restrict__ counter) {
    __shared__ __align__(16) u16 xs[2 * 191 * 64];       // 47.75 KB x window
    __shared__ int sh;

    const int tid  = threadIdx.x;
    const int lane = tid & 63, w = tid >> 6;
    const int m15  = lane & 15, q4 = lane >> 4;
    const int th   = w >> 1, batch = w & 1;              // wave = (t-half, batch)

    for (;;) {
        __syncthreads();                                 // xs/sh reuse guard
        if (tid == 0) sh = atomicAdd(counter, 1);
        __syncthreads();
        const int U = sh;
        if (U >= 1120) break;

        // taper: U<992 -> full unit; else half task (32-s) of unit 992+(U-992)/2
        int mu = U, shalf = 0, slen = 64;
        if (U >= 992) { mu = 992 + ((U - 992) >> 1); shalf = (U - 992) & 1; slen = 32; }
        // J-major unit decode: group g=J>>1, G(g)=g(65-g), column cnt=32-g
        int g = 0;
        #pragma unroll 1
        while (g < 31 && (g + 1) * (64 - g) <= mu) ++g;
        const int rem = mu - g * (65 - g);
        const int cnt = 32 - g;
        const int col = (rem >= cnt) ? 1 : 0;
        const int J = 2 * g + col;
        const int I = g + (col ? rem - cnt : rem);
        const int t0 = I << 7, s0 = (J << 6) + (shalf << 5);
        const int nrows = 127 + slen;
        const int base = 4096 + t0 - s0 - (slen - 1);    // window start row in xpad

        // ---- stage x window: nrows rows/batch ----
        #pragma unroll
        for (int b = 0; b < 2; ++b) {
            #pragma unroll 1
            for (int f = tid; f < nrows * 8; f += 256) {
                int r = f >> 3, c = f & 7;
                bf16x8 v = *(const bf16x8*)(xpad + (size_t)((b << 13) + base + r) * 64 + c * 8);
                *(bf16x8*)(xs + ((b * 191 + r) * 8 + (c ^ (r & 7))) * 8) = v;
            }
        }
        __syncthreads();                                 // window visible

        f32x4 acc[4][4];
        #pragma unroll
        for (int mt = 0; mt < 4; ++mt)
            #pragma unroll
            for (int nt = 0; nt < 4; ++nt)
                acc[mt][nt] = (f32x4){0.f, 0.f, 0.f, 0.f};

        const u16* xb = xs + batch * (191 * 64);
        const int rb = th * 64 + (slen - 1) + m15;       // + mt*16 - ds

#define LOADW(BUF, S)                                                          \
        {                                                                      \
            const u16* wp_ = wg + (size_t)(S) * 4096 + lane * 8;               \
            _Pragma("unroll")                                                  \
            for (int f = 0; f < 8; ++f) BUF[f] = *(const bf16x8*)(wp_ + f * 512); \
        }

#define COMPUTE_S(BUF, DS)                                                     \
        {                                                                      \
            const int ds_ = (DS);                                              \
            _Pragma("unroll")                                                  \
            for (int ks = 0; ks < 2; ++ks) {                                   \
                const int kq = ks * 4 + q4;                                    \
                _Pragma("unroll")                                              \
                for (int mt = 0; mt < 4; ++mt) {                               \
                    int r = rb + mt * 16 - ds_;                                \
                    bf16x8 av = *(const bf16x8*)(xb + (r * 8 + (kq ^ (r & 7))) * 8); \
                    acc[mt][0] = __builtin_amdgcn_mfma_f32_16x16x32_bf16(av, BUF[ks * 4 + 0], acc[mt][0], 0, 0, 0); \
                    acc[mt][1] = __builtin_amdgcn_mfma_f32_16x16x32_bf16(av, BUF[ks * 4 + 1], acc[mt][1], 0, 0, 0); \
                    acc[mt][2] = __builtin_amdgcn_mfma_f32_16x16x32_bf16(av, BUF[ks * 4 + 2], acc[mt][2], 0, 0, 0); \
                    acc[mt][3] = __builtin_amdgcn_mfma_f32_16x16x32_bf16(av, BUF[ks * 4 + 3], acc[mt][3], 0, 0, 0); \
                }                                                              \
            }                                                                  \
        }

        bf16x8 b0[8], b1[8], b2[8], b3[8];
        const int half = slen >> 1;                      // 32 or 16 (even)
        LOADW(b0, s0);     LOADW(b1, s0 + 1);
        LOADW(b2, s0 + 2); LOADW(b3, s0 + 3);
        #pragma unroll 1
        for (int j2 = 0; j2 < half; j2 += 2) {
            __builtin_amdgcn_s_setprio(1);
            COMPUTE_S(b0, 2 * j2);
            COMPUTE_S(b1, 2 * j2 + 1);
            __builtin_amdgcn_s_setprio(0);
            if (j2 + 2 < half) { LOADW(b0, s0 + 2 * j2 + 4); LOADW(b1, s0 + 2 * j2 + 5); }
            __builtin_amdgcn_s_setprio(1);
            COMPUTE_S(b2, 2 * j2 + 2);
            COMPUTE_S(b3, 2 * j2 + 3);
            __builtin_amdgcn_s_setprio(0);
            if (j2 + 2 < half) { LOADW(b2, s0 + 2 * j2 + 6); LOADW(b3, s0 + 2 * j2 + 7); }
        }
#undef LOADW
#undef COMPUTE_S

        // ---- epilogue: each wave writes its 64t x 64o tile ----
        #pragma unroll
        for (int mt = 0; mt < 4; ++mt) {
            int t = t0 + th * 64 + mt * 16 + q4 * 4;
            #pragma unroll
            for (int nt = 0; nt < 4; ++nt) {
                int o = nt * 16 + m15;
                float* op = out + (size_t)((batch << 12) + t) * 64 + o;
                #pragma unroll
                for (int r = 0; r < 4; ++r)
                    atomicAdd(op + r * 64, acc[mt][nt][r]);
            }
        }
    }
}

// ---------------------------------------------------------------------------
extern "C" void kernel_launch(void* const* d_in, const int* in_sizes, int n_in,
                              void* d_out, int out_size, void* d_ws, size_t ws_size,
                              hipStream_t stream) {
    const float* x   = (const float*)d_in[0];   // (2, 4096, 64)
    const float* phi = (const float*)d_in[1];   // (4096, 40)
    const float* M   = (const float*)d_in[2];   // (64, 64, 3)
    const float* Mp  = (const float*)d_in[3];   // (40, 64, 64)
    const float* Mm  = (const float*)d_in[4];   // (40, 64, 64)
    float* out = (float*)d_out;                 // (2, 4096, 64)

    // ws: [0,4096) counter | xpad 2 MiB | wg 32 MiB
    int* counter = (int*)d_ws;
    u16* xpad = (u16*)((char*)d_ws + 4096);
    u16* wg   = (u16*)((char*)d_ws + 4096 + 2097152);

    k_mid<<<896, 256, 0, stream>>>(x, xpad, phi, Mp, Mm, M, wg, out, counter);
    k_spectral<<<512, 256, 0, stream>>>(xpad, wg, out, counter);
}